// Round 10
// baseline (153.254 us; speedup 1.0000x reference)
//
#include <hip/hip_runtime.h>
#include <hip/hip_bf16.h>

// x [B=4][C=256][N=4096] fp32 -> attention [B][N][N] fp32 (row softmax of cosine sim)
#define BATCH 4
#define CDIM  256
#define NTOK  4096

#define BM 64      // rows per block
#define BN 128     // tokens per ct tile; staged as 4 sub-chunks of 128 tok x 64 k (16 KB)

typedef short bf16x8 __attribute__((ext_vector_type(8)));
typedef float floatx4 __attribute__((ext_vector_type(4)));
typedef unsigned int uintx4 __attribute__((ext_vector_type(4)));
typedef unsigned int u32;

#define PIN(v) asm volatile("" : "+v"(v))
#define WAIT(n) asm volatile("s_waitcnt vmcnt(" #n ")" ::: "memory")
#define BAR() do { __builtin_amdgcn_s_barrier(); asm volatile("" ::: "memory"); } while (0)

__device__ inline u32 f2bf1(float f) {
    u32 u = __float_as_uint(f);
    u += 0x7fffu + ((u >> 16) & 1u);   // RTNE
    return u >> 16;
}
__device__ inline u32 f2bf2(float lo, float hi) { return f2bf1(lo) | (f2bf1(hi) << 16); }

__device__ inline void gload_lds16(const short* g, short* l) {
    __builtin_amdgcn_global_load_lds(
        (const __attribute__((address_space(1))) u32*)g,
        (__attribute__((address_space(3))) u32*)l, 16, 0, 0);
}

// ---------- prep: x [B][C][N] f32 -> xn [B][N][C] bf16, rows normalized to unit L2 ----------
#define TT 32
__global__ __launch_bounds__(256) void prep_kernel(const float* __restrict__ x,
                                                   short* __restrict__ xn) {
    __shared__ float tile[TT][CDIM + 2];
    __shared__ float part[8][TT];
    __shared__ float rinv_s[TT];
    const int tid = threadIdx.x;
    const int blk = blockIdx.x;            // 0..511
    const int b = blk >> 7;
    const int t0 = (blk & 127) * TT;
    const float* xb = x + (size_t)b * CDIM * NTOK;
    const int ti = tid & 31, cq = tid >> 5;
    float ss = 0.f;
    for (int c = cq; c < CDIM; c += 8) {
        float v = xb[(size_t)c * NTOK + t0 + ti];
        tile[ti][c] = v;
        ss += v * v;
    }
    part[cq][ti] = ss;
    __syncthreads();
    if (tid < TT) {
        float s = 0.f;
#pragma unroll
        for (int q = 0; q < 8; ++q) s += part[q][tid];
        rinv_s[tid] = 1.0f / sqrtf(s);
    }
    __syncthreads();
    const int tok = tid >> 3, seg = tid & 7;
    const float ri = rinv_s[tok];
    size_t obase = ((size_t)(b * NTOK + t0 + tok)) * CDIM + seg * 32;
#pragma unroll
    for (int j = 0; j < 4; ++j) {
        u32 w[4];
#pragma unroll
        for (int u = 0; u < 4; ++u) {
            float f0 = tile[tok][seg * 32 + j * 8 + 2 * u] * ri;
            float f1 = tile[tok][seg * 32 + j * 8 + 2 * u + 1] * ri;
            w[u] = f2bf2(f0, f1);
        }
        *(uintx4*)&xn[obase + j * 8] = (uintx4){w[0], w[1], w[2], w[3]};
    }
}

// ---------- fused two-sweep GEMM + softmax, counted-vmcnt 4-deep ring ----------
// Block: 64 rows x 4096 cols, K=256, 8 waves (2 row x 4 col). A pinned in regs.
// Sub-chunk t = 4*ct + kc = 128 tok x 64 k (16 KB) in ring slot Bs[kc] (STATIC idx).
// Prefetch depth 2; counted vmcnt; raw s_barrier per sub-chunk.
// 2 blocks/CU (launch_bounds 512,4; VGPR cap 128) so two independent pipelines
// co-schedule per CU — they stall at different points, unlike a drain barrier.
__global__ __launch_bounds__(512, 4) void attn_kernel(const short* __restrict__ xn,
                                                      float* __restrict__ out) {
    __shared__ short Bs[4][128][64];      // 4 x 16 KB ring
    __shared__ float rowsumLds[BM][4];
    const int tid = threadIdx.x;
    const int D = blockIdx.x;
    const int b = D >> 6;
    const int rb = (D & 63) * BM;
    const short* xnb = xn + (size_t)b * NTOK * CDIM;
    float* outb = out + ((size_t)b << 24);
    const int lane = tid & 63, wid = tid >> 6;     // 8 waves: 2 row x 4 col
    const int wr = (wid >> 2) * 32;
    const int wc = (wid & 3) * 32;
    const int r0 = lane & 15, kq = lane >> 4;
    const int sx = r0 & 7;                         // tr & 7 for both n-tiles
    const int tr0 = wc + r0, tr1 = wc + 16 + r0;

    // staging roles (per wave): rows wid*8..+7 (and +64)
    const int trl0 = (wid << 3) + (lane >> 3);
    const int c8 = (lane & 7) ^ (lane >> 3);       // inverse-swizzled source 16B-chunk

    // A fragments: rows rb + wr + m*16 + r0, full K=256 in registers, PINNED
    bf16x8 afr[2][8];
#pragma unroll
    for (int m = 0; m < 2; ++m) {
        const short* arow = xnb + (size_t)(rb + wr + m * 16 + r0) * CDIM;
#pragma unroll
        for (int j = 0; j < 8; ++j) {
            afr[m][j] = *(const bf16x8*)(arow + j * 32 + kq * 8);
            PIN(afr[m][j]);
        }
    }

    // psum holds rowsums during sweep 0, then is replaced in-place by rinv.
    float psum0[4] = {0.f, 0.f, 0.f, 0.f}, psum1[4] = {0.f, 0.f, 0.f, 0.f};
    floatx4 acc00, acc01, acc10, acc11;

    auto stage = [&](int ct, int kc) {
        const short* s0 = xnb + (size_t)(ct * BN + trl0) * CDIM + kc * 64 + c8 * 8;
        short* d = &Bs[kc][wid << 3][0];
        gload_lds16(s0, d);
        gload_lds16(s0 + (size_t)64 * CDIM, d + 64 * 64);
    };

#define ACCZERO() do { acc00 = (floatx4){0,0,0,0}; acc01 = (floatx4){0,0,0,0}; \
                       acc10 = (floatx4){0,0,0,0}; acc11 = (floatx4){0,0,0,0}; } while (0)

#define COMPUTE(KC) do { \
    __builtin_amdgcn_s_setprio(1); \
    const int p0 = kq ^ sx, p1 = (4 | kq) ^ sx; \
    bf16x8 b0a = *(const bf16x8*)&Bs[KC][tr0][p0 * 8]; \
    bf16x8 b1a = *(const bf16x8*)&Bs[KC][tr1][p0 * 8]; \
    acc00 = __builtin_amdgcn_mfma_f32_16x16x32_bf16(afr[0][(KC)*2],   b0a, acc00, 0,0,0); \
    acc10 = __builtin_amdgcn_mfma_f32_16x16x32_bf16(afr[1][(KC)*2],   b0a, acc10, 0,0,0); \
    acc01 = __builtin_amdgcn_mfma_f32_16x16x32_bf16(afr[0][(KC)*2],   b1a, acc01, 0,0,0); \
    acc11 = __builtin_amdgcn_mfma_f32_16x16x32_bf16(afr[1][(KC)*2],   b1a, acc11, 0,0,0); \
    bf16x8 b0b = *(const bf16x8*)&Bs[KC][tr0][p1 * 8]; \
    bf16x8 b1b = *(const bf16x8*)&Bs[KC][tr1][p1 * 8]; \
    acc00 = __builtin_amdgcn_mfma_f32_16x16x32_bf16(afr[0][(KC)*2+1], b0b, acc00, 0,0,0); \
    acc10 = __builtin_amdgcn_mfma_f32_16x16x32_bf16(afr[1][(KC)*2+1], b0b, acc10, 0,0,0); \
    acc01 = __builtin_amdgcn_mfma_f32_16x16x32_bf16(afr[0][(KC)*2+1], b1b, acc01, 0,0,0); \
    acc11 = __builtin_amdgcn_mfma_f32_16x16x32_bf16(afr[1][(KC)*2+1], b1b, acc11, 0,0,0); \
    __builtin_amdgcn_s_setprio(0); \
} while (0)

#define STEP(KC, SCT, SKC, WN) do { stage((SCT), (SKC)); WAIT(WN); BAR(); COMPUTE(KC); } while (0)
#define STEPNS(KC, WN)        do { WAIT(WN); BAR(); COMPUTE(KC); } while (0)

#define EPI0() do { \
    _Pragma("unroll") for (int r = 0; r < 4; ++r) { \
        psum0[r] += __expf(acc00[r] - 1.f) + __expf(acc01[r] - 1.f); \
        psum1[r] += __expf(acc10[r] - 1.f) + __expf(acc11[r] - 1.f); } \
} while (0)

#define EPI1(CT) do { \
    _Pragma("unroll") for (int r = 0; r < 4; ++r) { \
        const int row_a = rb + wr + kq * 4 + r; \
        float* pa = outb + ((size_t)row_a << 12) + ((CT) << 7) + wc + r0; \
        __builtin_nontemporal_store(__expf(acc00[r] - 1.f) * psum0[r], pa); \
        __builtin_nontemporal_store(__expf(acc01[r] - 1.f) * psum0[r], pa + 16); \
        float* pb = pa + ((size_t)16 << 12); \
        __builtin_nontemporal_store(__expf(acc10[r] - 1.f) * psum1[r], pb); \
        __builtin_nontemporal_store(__expf(acc11[r] - 1.f) * psum1[r], pb + 16); } \
} while (0)

    // ================= sweep 0: rowsums =================
    stage(0, 0); stage(0, 1);
    for (int ct = 0; ct < 31; ++ct) {
        ACCZERO();
        STEP(0, ct, 2, 4);
        STEP(1, ct, 3, 4);
        STEP(2, ct + 1, 0, 4);
        STEP(3, ct + 1, 1, 4);
        EPI0();
    }
    ACCZERO();
    STEP(0, 31, 2, 4);
    STEP(1, 31, 3, 4);
    STEPNS(2, 2);
    STEPNS(3, 0);
    EPI0();

    // rowsum reduce -> rinv (stored back into psum)
#pragma unroll
    for (int r = 0; r < 4; ++r) {
        float v0 = psum0[r], v1 = psum1[r];
        v0 += __shfl_xor(v0, 1); v0 += __shfl_xor(v0, 2);
        v0 += __shfl_xor(v0, 4); v0 += __shfl_xor(v0, 8);
        v1 += __shfl_xor(v1, 1); v1 += __shfl_xor(v1, 2);
        v1 += __shfl_xor(v1, 4); v1 += __shfl_xor(v1, 8);
        if (r0 == 0) {
            rowsumLds[wr + kq * 4 + r][wid & 3] = v0;
            rowsumLds[wr + 16 + kq * 4 + r][wid & 3] = v1;
        }
    }
    __syncthreads();
#pragma unroll
    for (int r = 0; r < 4; ++r) {
        const int ra = wr + kq * 4 + r, rbw = wr + 16 + kq * 4 + r;
        psum0[r] = 1.0f / (rowsumLds[ra][0] + rowsumLds[ra][1] + rowsumLds[ra][2] + rowsumLds[ra][3]);
        psum1[r] = 1.0f / (rowsumLds[rbw][0] + rowsumLds[rbw][1] + rowsumLds[rbw][2] + rowsumLds[rbw][3]);
    }
    __syncthreads();   // also guards ring reuse below

    // ================= sweep 1: normalized stores =================
    stage(0, 0); stage(0, 1);
    {   // ct = 0 peeled (no stores outstanding yet -> waits of 4)
        ACCZERO();
        STEP(0, 0, 2, 4);
        STEP(1, 0, 3, 4);
        STEP(2, 1, 0, 4);
        STEP(3, 1, 1, 4);
        EPI1(0);
    }
    for (int ct = 1; ct < 31; ++ct) {
        ACCZERO();
        STEP(0, ct, 2, 12);      // 8 stores of ct-1 sit between counted loads
        STEP(1, ct, 3, 12);
        STEP(2, ct + 1, 0, 4);
        STEP(3, ct + 1, 1, 4);
        EPI1(ct);
    }
    ACCZERO();
    STEP(0, 31, 2, 12);
    STEP(1, 31, 3, 12);
    STEPNS(2, 2);
    STEPNS(3, 0);
    EPI1(31);

#undef ACCZERO
#undef COMPUTE
#undef STEP
#undef STEPNS
#undef EPI0
#undef EPI1
}

extern "C" void kernel_launch(void* const* d_in, const int* in_sizes, int n_in,
                              void* d_out, int out_size, void* d_ws, size_t ws_size,
                              hipStream_t stream) {
    const float* x = (const float*)d_in[0];
    float* out = (float*)d_out;
    short* xn = (short*)d_ws;    // [B][N][C] bf16 = 8 MB

    prep_kernel<<<BATCH * (NTOK / TT), 256, 0, stream>>>(x, xn);
    attn_kernel<<<NTOK / BM * BATCH, 512, 0, stream>>>(xn, out);
}

// Round 11
// 145.500 us; speedup vs baseline: 1.0533x; 1.0533x over previous
//
#include <hip/hip_runtime.h>
#include <hip/hip_bf16.h>

// x [B=4][C=256][N=4096] fp32 -> attention [B][N][N] fp32 (row softmax of cosine sim)
#define BATCH 4
#define CDIM  256
#define NTOK  4096

#define BM 64      // rows per block
#define BN 128     // tokens per ct tile; staged as 4 sub-chunks of 128 tok x 64 k (16 KB)

typedef short bf16x8 __attribute__((ext_vector_type(8)));
typedef float floatx4 __attribute__((ext_vector_type(4)));
typedef unsigned int uintx4 __attribute__((ext_vector_type(4)));
typedef unsigned int u32;

#define PIN(v) asm volatile("" : "+v"(v))
#define WAIT(n) asm volatile("s_waitcnt vmcnt(" #n ")" ::: "memory")
#define LGKM0() asm volatile("s_waitcnt lgkmcnt(0)" ::: "memory")
#define BAR() do { __builtin_amdgcn_s_barrier(); asm volatile("" ::: "memory"); } while (0)

__device__ inline u32 f2bf1(float f) {
    u32 u = __float_as_uint(f);
    u += 0x7fffu + ((u >> 16) & 1u);   // RTNE
    return u >> 16;
}
__device__ inline u32 f2bf2(float lo, float hi) { return f2bf1(lo) | (f2bf1(hi) << 16); }

__device__ inline void gload_lds16(const short* g, short* l) {
    __builtin_amdgcn_global_load_lds(
        (const __attribute__((address_space(1))) u32*)g,
        (__attribute__((address_space(3))) u32*)l, 16, 0, 0);
}

// ---------- prep: x [B][C][N] f32 -> xn [B][N][C] bf16, rows normalized to unit L2 ----------
#define TT 32
__global__ __launch_bounds__(256) void prep_kernel(const float* __restrict__ x,
                                                   short* __restrict__ xn) {
    __shared__ float tile[TT][CDIM + 2];
    __shared__ float part[8][TT];
    __shared__ float rinv_s[TT];
    const int tid = threadIdx.x;
    const int blk = blockIdx.x;            // 0..511
    const int b = blk >> 7;
    const int t0 = (blk & 127) * TT;
    const float* xb = x + (size_t)b * CDIM * NTOK;
    const int ti = tid & 31, cq = tid >> 5;
    float ss = 0.f;
    for (int c = cq; c < CDIM; c += 8) {
        float v = xb[(size_t)c * NTOK + t0 + ti];
        tile[ti][c] = v;
        ss += v * v;
    }
    part[cq][ti] = ss;
    __syncthreads();
    if (tid < TT) {
        float s = 0.f;
#pragma unroll
        for (int q = 0; q < 8; ++q) s += part[q][tid];
        rinv_s[tid] = 1.0f / sqrtf(s);
    }
    __syncthreads();
    const int tok = tid >> 3, seg = tid & 7;
    const float ri = rinv_s[tok];
    size_t obase = ((size_t)(b * NTOK + t0 + tok)) * CDIM + seg * 32;
#pragma unroll
    for (int j = 0; j < 4; ++j) {
        u32 w[4];
#pragma unroll
        for (int u = 0; u < 4; ++u) {
            float f0 = tile[tok][seg * 32 + j * 8 + 2 * u] * ri;
            float f1 = tile[tok][seg * 32 + j * 8 + 2 * u + 1] * ri;
            w[u] = f2bf2(f0, f1);
        }
        *(uintx4*)&xn[obase + j * 8] = (uintx4){w[0], w[1], w[2], w[3]};
    }
}

// ---------- fused two-sweep GEMM + softmax, counted-vmcnt ring + LDS-staged stores ----------
// Sweep 0 identical to R9. Sweep 1: per-ct output tile goes acc -> Co[64][132] fp32
// in LDS -> cooperative 512-B-contiguous nontemporal dwordx4 streams (store phase SP,
// pipelined one ct behind compute via accP). vmcnt accounting includes the 4 store
// instrs per wave sitting in the queue: WAIT 4/4/8/8 per ct steady state.
__global__ __launch_bounds__(512, 2) void attn_kernel(const short* __restrict__ xn,
                                                      float* __restrict__ out) {
    __shared__ short Bs[4][128][64];      // 4 x 16 KB ring
    __shared__ float Co[64][132];         // 33 KB out-tile (stride 132: 16B-aligned rows, <=2-way banks)
    __shared__ float rowsumLds[BM][4];
    const int tid = threadIdx.x;
    const int D = blockIdx.x;
    const int b = D >> 6;
    const int rb = (D & 63) * BM;
    const short* xnb = xn + (size_t)b * NTOK * CDIM;
    float* outb = out + ((size_t)b << 24);
    const int lane = tid & 63, wid = tid >> 6;     // 8 waves: 2 row x 4 col
    const int wr = (wid >> 2) * 32;
    const int wc = (wid & 3) * 32;
    const int r0 = lane & 15, kq = lane >> 4;
    const int sx = r0 & 7;
    const int tr0 = wc + r0, tr1 = wc + 16 + r0;

    const int trl0 = (wid << 3) + (lane >> 3);
    const int c8 = (lane & 7) ^ (lane >> 3);       // inverse-swizzled source 16B-chunk

    // A fragments: rows rb + wr + m*16 + r0, full K=256 in registers, PINNED
    bf16x8 afr[2][8];
#pragma unroll
    for (int m = 0; m < 2; ++m) {
        const short* arow = xnb + (size_t)(rb + wr + m * 16 + r0) * CDIM;
#pragma unroll
        for (int j = 0; j < 8; ++j) {
            afr[m][j] = *(const bf16x8*)(arow + j * 32 + kq * 8);
            PIN(afr[m][j]);
        }
    }

    float psum0[4] = {0.f, 0.f, 0.f, 0.f}, psum1[4] = {0.f, 0.f, 0.f, 0.f};
    float rinv0[4], rinv1[4];
    floatx4 acc00, acc01, acc10, acc11;
    floatx4 accP00, accP01, accP10, accP11;

    auto stage = [&](int ct, int kc) {
        const short* s0 = xnb + (size_t)(ct * BN + trl0) * CDIM + kc * 64 + c8 * 8;
        short* d = &Bs[kc][wid << 3][0];
        gload_lds16(s0, d);
        gload_lds16(s0 + (size_t)64 * CDIM, d + 64 * 64);
    };

#define ACCZERO() do { acc00 = (floatx4){0,0,0,0}; acc01 = (floatx4){0,0,0,0}; \
                       acc10 = (floatx4){0,0,0,0}; acc11 = (floatx4){0,0,0,0}; } while (0)
#define SAVEACC() do { accP00 = acc00; accP01 = acc01; accP10 = acc10; accP11 = acc11; } while (0)

#define COMPUTE(KC) do { \
    __builtin_amdgcn_s_setprio(1); \
    const int p0 = kq ^ sx, p1 = (4 | kq) ^ sx; \
    bf16x8 b0a = *(const bf16x8*)&Bs[KC][tr0][p0 * 8]; \
    bf16x8 b1a = *(const bf16x8*)&Bs[KC][tr1][p0 * 8]; \
    bf16x8 b0b = *(const bf16x8*)&Bs[KC][tr0][p1 * 8]; \
    bf16x8 b1b = *(const bf16x8*)&Bs[KC][tr1][p1 * 8]; \
    acc00 = __builtin_amdgcn_mfma_f32_16x16x32_bf16(afr[0][(KC)*2],   b0a, acc00, 0,0,0); \
    acc10 = __builtin_amdgcn_mfma_f32_16x16x32_bf16(afr[1][(KC)*2],   b0a, acc10, 0,0,0); \
    acc01 = __builtin_amdgcn_mfma_f32_16x16x32_bf16(afr[0][(KC)*2],   b1a, acc01, 0,0,0); \
    acc11 = __builtin_amdgcn_mfma_f32_16x16x32_bf16(afr[1][(KC)*2],   b1a, acc11, 0,0,0); \
    acc00 = __builtin_amdgcn_mfma_f32_16x16x32_bf16(afr[0][(KC)*2+1], b0b, acc00, 0,0,0); \
    acc10 = __builtin_amdgcn_mfma_f32_16x16x32_bf16(afr[1][(KC)*2+1], b0b, acc10, 0,0,0); \
    acc01 = __builtin_amdgcn_mfma_f32_16x16x32_bf16(afr[0][(KC)*2+1], b1b, acc01, 0,0,0); \
    acc11 = __builtin_amdgcn_mfma_f32_16x16x32_bf16(afr[1][(KC)*2+1], b1b, acc11, 0,0,0); \
    __builtin_amdgcn_s_setprio(0); \
} while (0)

#define STEP(KC, SCT, SKC, WN) do { stage((SCT), (SKC)); WAIT(WN); BAR(); COMPUTE(KC); } while (0)
#define STEPNS(KC, WN)        do { WAIT(WN); BAR(); COMPUTE(KC); } while (0)

#define EPI0() do { \
    _Pragma("unroll") for (int r = 0; r < 4; ++r) { \
        psum0[r] += __expf(acc00[r] - 1.f) + __expf(acc01[r] - 1.f); \
        psum1[r] += __expf(acc10[r] - 1.f) + __expf(acc11[r] - 1.f); } \
} while (0)

// Store phase: accP (ct=CT's result) -> Co -> contiguous nontemporal streams.
#define SP(CT) do { \
    _Pragma("unroll") for (int r = 0; r < 4; ++r) { \
        const int rowa = wr + kq * 4 + r; \
        Co[rowa][wc + r0]           = __expf(accP00[r] - 1.f) * rinv0[r]; \
        Co[rowa][wc + 16 + r0]      = __expf(accP01[r] - 1.f) * rinv0[r]; \
        Co[rowa + 16][wc + r0]      = __expf(accP10[r] - 1.f) * rinv1[r]; \
        Co[rowa + 16][wc + 16 + r0] = __expf(accP11[r] - 1.f) * rinv1[r]; } \
    LGKM0(); \
    BAR(); \
    _Pragma("unroll") for (int p = 0; p < 4; ++p) { \
        const int rw = (wid << 3) + (lane >> 5) + 2 * p; \
        floatx4 v = *(const floatx4*)&Co[rw][(lane & 31) * 4]; \
        __builtin_nontemporal_store(v, \
            (floatx4*)(outb + (((size_t)(rb + rw)) << 12) + ((CT) << 7) + (lane & 31) * 4)); } \
} while (0)

    // ================= sweep 0: rowsums (R9 verbatim) =================
    stage(0, 0); stage(0, 1);
    for (int ct = 0; ct < 31; ++ct) {
        ACCZERO();
        STEP(0, ct, 2, 4);
        STEP(1, ct, 3, 4);
        STEP(2, ct + 1, 0, 4);
        STEP(3, ct + 1, 1, 4);
        EPI0();
    }
    ACCZERO();
    STEP(0, 31, 2, 4);
    STEP(1, 31, 3, 4);
    STEPNS(2, 2);
    STEPNS(3, 0);
    EPI0();

    // rowsum reduce -> rinv
#pragma unroll
    for (int r = 0; r < 4; ++r) {
        float v0 = psum0[r], v1 = psum1[r];
        v0 += __shfl_xor(v0, 1); v0 += __shfl_xor(v0, 2);
        v0 += __shfl_xor(v0, 4); v0 += __shfl_xor(v0, 8);
        v1 += __shfl_xor(v1, 1); v1 += __shfl_xor(v1, 2);
        v1 += __shfl_xor(v1, 4); v1 += __shfl_xor(v1, 8);
        if (r0 == 0) {
            rowsumLds[wr + kq * 4 + r][wid & 3] = v0;
            rowsumLds[wr + 16 + kq * 4 + r][wid & 3] = v1;
        }
    }
    __syncthreads();
#pragma unroll
    for (int r = 0; r < 4; ++r) {
        const int ra = wr + kq * 4 + r, rbw = wr + 16 + kq * 4 + r;
        rinv0[r] = 1.0f / (rowsumLds[ra][0] + rowsumLds[ra][1] + rowsumLds[ra][2] + rowsumLds[ra][3]);
        rinv1[r] = 1.0f / (rowsumLds[rbw][0] + rowsumLds[rbw][1] + rowsumLds[rbw][2] + rowsumLds[rbw][3]);
    }
    __syncthreads();   // also guards ring reuse below

    // ================= sweep 1: compute + pipelined store phase =================
    stage(0, 0); stage(0, 1);
    ACCZERO();
    STEP(0, 0, 2, 4);
    STEP(1, 0, 3, 4);
    STEP(2, 1, 0, 4);
    STEP(3, 1, 1, 4);
    SAVEACC();
    for (int ct = 1; ct < 31; ++ct) {
        ACCZERO();
        STEP(0, ct, 2, 4);       // WAIT(4): retires prev SP's 4 stores + this ct's first loads
        STEP(1, ct, 3, 4);
        SP(ct - 1);              // stores fly; counted in queue below
        STEP(2, ct + 1, 0, 8);   // leave 4S + 4L in flight
        STEP(3, ct + 1, 1, 8);
        SAVEACC();
    }
    ACCZERO();
    STEP(0, 31, 2, 4);
    STEP(1, 31, 3, 4);
    SP(30);
    STEPNS(2, 6);                // [2L 2L 4S] -> need oldest 2L
    STEPNS(3, 4);                // [2L 4S]    -> need 2L
    SAVEACC();
    SP(31);

#undef ACCZERO
#undef SAVEACC
#undef COMPUTE
#undef STEP
#undef STEPNS
#undef EPI0
#undef SP
}

extern "C" void kernel_launch(void* const* d_in, const int* in_sizes, int n_in,
                              void* d_out, int out_size, void* d_ws, size_t ws_size,
                              hipStream_t stream) {
    const float* x = (const float*)d_in[0];
    float* out = (float*)d_out;
    short* xn = (short*)d_ws;    // [B][N][C] bf16 = 8 MB

    prep_kernel<<<BATCH * (NTOK / TT), 256, 0, stream>>>(x, xn);
    attn_kernel<<<NTOK / BM * BATCH, 512, 0, stream>>>(xn, out);
}